// Round 4
// baseline (5901.598 us; speedup 1.0000x reference)
//
#include <hip/hip_runtime.h>
#include <cmath>

typedef _Float16 f16;
typedef _Float16 f16x8 __attribute__((ext_vector_type(8)));
typedef float f32x4 __attribute__((ext_vector_type(4)));

#define DH 256
#define G3 768
#define DIN 300
#define KL 320
#define NLEAF 16384
#define NBLK 512
#define NTHR 256
#define NWAVE ((NBLK*NTHR)/64)   // 2048

__device__ __forceinline__ float sigm(float x){ return 1.0f/(1.0f+expf(-x)); }

__device__ __forceinline__ f32x4 mfma3(f16x8 ah, f16x8 al, f16x8 bh, f16x8 bl, f32x4 acc){
    acc = __builtin_amdgcn_mfma_f32_16x16x32_f16(ah, bh, acc, 0,0,0);
    acc = __builtin_amdgcn_mfma_f32_16x16x32_f16(ah, bl, acc, 0,0,0);
    acc = __builtin_amdgcn_mfma_f32_16x16x32_f16(al, bh, acc, 0,0,0);
    return acc;
}

// Device-scope grid barrier: generation counter + arrival count in global ws.
// Requires all NBLK blocks co-resident (guaranteed: 512 blocks, 256 thr,
// launch_bounds(256,2) => VGPR<=256 => 2 blocks/CU => 512 fit on 256 CUs).
__device__ __forceinline__ void gbar(int* cnt, int* gen){
    __syncthreads();
    if (threadIdx.x == 0){
        __threadfence();   // flush this block's writes device-wide
        int g = __hip_atomic_load(gen, __ATOMIC_RELAXED, __HIP_MEMORY_SCOPE_AGENT);
        int old = __hip_atomic_fetch_add(cnt, 1, __ATOMIC_ACQ_REL, __HIP_MEMORY_SCOPE_AGENT);
        if (old == NBLK-1){
            __hip_atomic_store(cnt, 0, __ATOMIC_RELAXED, __HIP_MEMORY_SCOPE_AGENT);
            __hip_atomic_store(gen, g+1, __ATOMIC_RELEASE, __HIP_MEMORY_SCOPE_AGENT);
        } else {
            while (__hip_atomic_load(gen, __ATOMIC_ACQUIRE, __HIP_MEMORY_SCOPE_AGENT) == g)
                __builtin_amdgcn_s_sleep(2);
        }
        __threadfence();   // acquire: invalidate stale L1/L2 before reading others' data
    }
    __syncthreads();
}

// ---- prep1: weight transpose/split + barrier init ----
__global__ void prep_kernel(const float* __restrict__ Wx, const float* __restrict__ Wc,
                            const float* __restrict__ Ws, const float* __restrict__ bx,
                            const float* __restrict__ bs, const float* __restrict__ bc,
                            f16* __restrict__ BLh, f16* __restrict__ BLl,
                            f16* __restrict__ B1h, f16* __restrict__ B1l,
                            f16* __restrict__ B2h, f16* __restrict__ B2l,
                            float* __restrict__ bL, float* __restrict__ b1, float* __restrict__ b2,
                            int* __restrict__ bar){
    if (blockIdx.x == 0 && threadIdx.x == 0){ bar[0] = 0; bar[1] = 0; }
    int idx = blockIdx.x*256 + threadIdx.x;
    const int nBL = G3*KL, nB1 = 512*DH, nB2 = G3*512;
    if (idx < nBL){
        int m = idx / KL, k = idx - m*KL;
        int blk = m/48, rem = m - blk*48, g = rem>>4, j = blk*16 + (rem&15);
        float v = (k < DIN) ? Wx[k*G3 + g*DH + j] : 0.0f;
        f16 h = (f16)v; BLh[idx] = h; BLl[idx] = (f16)(v - (float)h);
        return;
    }
    idx -= nBL;
    if (idx < nB1){
        int m = idx >> 8, k = idx & 255;
        int blk = m>>5, rem = m & 31, gg = rem>>4, j = blk*16 + (rem&15);
        float v = Wc[k*G3 + (gg+1)*DH + j];
        f16 h = (f16)v; B1h[idx] = h; B1l[idx] = (f16)(v - (float)h);
        return;
    }
    idx -= nB1;
    if (idx < nB2){
        int m = idx >> 9, k = idx & 511;
        int blk = m/48, rem = m - blk*48, g = rem>>4, j = blk*16 + (rem&15);
        float v = (k < DH) ? Wc[k*G3 + g*DH + j] : Ws[(k-DH)*G3 + g*DH + j];
        f16 h = (f16)v; B2h[idx] = h; B2l[idx] = (f16)(v - (float)h);
        return;
    }
    idx -= nB2;
    if (idx < G3){
        int blk = idx/48, rem = idx - blk*48, g = rem>>4, j = blk*16 + (rem&15);
        bL[idx] = bx[g*DH + j]; return;
    }
    idx -= G3;
    if (idx < 512){
        int blk = idx>>5, rem = idx & 31, gg = rem>>4, j = blk*16 + (rem&15);
        b1[idx] = bc[(gg+1)*DH+j] + bs[(gg+1)*DH+j]; return;
    }
    idx -= 512;
    if (idx < G3){
        int blk = idx/48, rem = idx - blk*48, g = rem>>4, j = blk*16 + (rem&15);
        b2[idx] = bc[g*DH+j] + bs[g*DH+j];
    }
}

// ---- prep2: gather leaf embedding rows and pre-split to f16 hi/lo ----
__global__ void gather_kernel(const int* __restrict__ wid, const float* __restrict__ emb,
                              f16* __restrict__ Xh, f16* __restrict__ Xl){
    int idx = blockIdx.x*256 + threadIdx.x;        // over NLEAF*KL
    int r = idx / KL, k = idx - r*KL;
    float v = (k < DIN) ? emb[wid[r]*DIN + k] : 0.0f;
    f16 h = (f16)v;
    Xh[idx] = h; Xl[idx] = (f16)(v - (float)h);
}

// ---- leaf: pure split-f16 MFMA GEMM [16384 x 320] @ BL -> gated h,c ----
__global__ __launch_bounds__(256) void leaf_kernel(
    const f16* __restrict__ Xh, const f16* __restrict__ Xl,
    const f16* __restrict__ BLh, const f16* __restrict__ BLl, const float* __restrict__ bL,
    f16* __restrict__ Hh, f16* __restrict__ Hl, float* __restrict__ C)
{
    const int tid = threadIdx.x;
    const int lane = tid & 63, w = tid >> 6;
    const int cg = blockIdx.y*4 + w;               // 0..15
    const int l15 = lane & 15, lg = lane >> 4;
    const int rowbase = blockIdx.x * 64;

    f32x4 acc[4][3];
    #pragma unroll
    for (int rt=0;rt<4;++rt)
      #pragma unroll
      for (int g=0;g<3;++g){ f32x4 z={0.f,0.f,0.f,0.f}; acc[rt][g]=z; }

    int ax[4];
    #pragma unroll
    for (int rt=0;rt<4;++rt) ax[rt] = (rowbase + rt*16 + l15)*KL + lg*8;
    const int m0 = (cg*48 + l15)*KL + lg*8;
    const int m1 = m0 + 16*KL;
    const int m2 = m1 + 16*KL;

    #pragma unroll 2
    for (int kst=0; kst<10; ++kst){
        const int ko = kst*32;
        f16x8 bh0 = *(const f16x8*)(BLh + m0 + ko);
        f16x8 bl0 = *(const f16x8*)(BLl + m0 + ko);
        f16x8 bh1 = *(const f16x8*)(BLh + m1 + ko);
        f16x8 bl1 = *(const f16x8*)(BLl + m1 + ko);
        f16x8 bh2 = *(const f16x8*)(BLh + m2 + ko);
        f16x8 bl2 = *(const f16x8*)(BLl + m2 + ko);
        #pragma unroll
        for (int rt=0;rt<4;++rt){
            f16x8 ah = *(const f16x8*)(Xh + ax[rt] + ko);
            f16x8 al = *(const f16x8*)(Xl + ax[rt] + ko);
            acc[rt][0] = mfma3(ah, al, bh0, bl0, acc[rt][0]);
            acc[rt][1] = mfma3(ah, al, bh1, bl1, acc[rt][1]);
            acc[rt][2] = mfma3(ah, al, bh2, bl2, acc[rt][2]);
        }
    }
    const int j = cg*16 + l15;
    const float bv0 = bL[cg*48 + l15];
    const float bv1 = bL[cg*48 + 16 + l15];
    const float bv2 = bL[cg*48 + 32 + l15];
    #pragma unroll
    for (int rt=0;rt<4;++rt){
      #pragma unroll
      for (int reg=0;reg<4;++reg){
        const int r = rowbase + rt*16 + lg*4 + reg;
        float gi = acc[rt][0][reg] + bv0;
        float go = acc[rt][1][reg] + bv1;
        float cp = acc[rt][2][reg] + bv2;
        float c = sigm(gi)*tanhf(cp);
        float h = sigm(go)*tanhf(c);
        C[r*DH + j] = c;
        f16 hh = (f16)h;
        Hh[r*DH + j] = hh;
        Hl[r*DH + j] = (f16)(h - (float)hh);
      }
    }
}

// ---- persistent tree kernel: all 14 levels + root, grid barriers between ----
__global__ __launch_bounds__(256, 2) void tree_kernel(
    f16* __restrict__ Hh, f16* __restrict__ Hl, float* __restrict__ C,
    f16* __restrict__ HLh, f16* __restrict__ HLl,
    const f16* __restrict__ B1h, const f16* __restrict__ B1l,
    const f16* __restrict__ B2h, const f16* __restrict__ B2l,
    const float* __restrict__ b1, const float* __restrict__ b2,
    float* __restrict__ out, int* __restrict__ bar)
{
    const int tid = threadIdx.x;
    const int gw = (blockIdx.x*NTHR + tid) >> 6;   // global wave id 0..2047
    const int lane = tid & 63, l15 = lane & 15, lg = lane >> 4;

    int s = 1;
    for (int P = NLEAF/2; P >= 1; P >>= 1){
        const int st = 2*s*DH;
        const int nt = ((P + 63) >> 6) * 16;
        // ---- K1: left-combine. task = (64 rows) x (16 cols x 2 gates) ----
        for (int t = gw; t < nt; t += NWAVE){
            const int rti = t >> 4, blk = t & 15;
            const int rowbase = rti << 6;
            f32x4 acc[4][2];
            #pragma unroll
            for (int rt=0;rt<4;++rt){ f32x4 z={0.f,0.f,0.f,0.f}; acc[rt][0]=z; acc[rt][1]=z; }
            int ao[4];
            #pragma unroll
            for (int rt=0;rt<4;++rt){
                int p = rowbase + rt*16 + l15; p = (p < P) ? p : P-1;
                ao[rt] = p*st + lg*8;
            }
            const int mb0 = (blk*32 + l15)*DH + lg*8;
            const int mb1 = mb0 + 16*DH;
            #pragma unroll 2
            for (int kst=0; kst<8; ++kst){
                const int ko = kst*32;
                f16x8 bh0 = *(const f16x8*)(B1h + mb0 + ko);
                f16x8 bl0 = *(const f16x8*)(B1l + mb0 + ko);
                f16x8 bh1 = *(const f16x8*)(B1h + mb1 + ko);
                f16x8 bl1 = *(const f16x8*)(B1l + mb1 + ko);
                #pragma unroll
                for (int rt=0;rt<4;++rt){
                    f16x8 ah = *(const f16x8*)(Hh + ao[rt] + ko);
                    f16x8 al = *(const f16x8*)(Hl + ao[rt] + ko);
                    acc[rt][0] = mfma3(ah, al, bh0, bl0, acc[rt][0]);
                    acc[rt][1] = mfma3(ah, al, bh1, bl1, acc[rt][1]);
                }
            }
            const int j = blk*16 + l15;
            const float bgc = b1[blk*32 + l15];
            const float bgo = b1[blk*32 + 16 + l15];
            #pragma unroll
            for (int rt=0;rt<4;++rt){
              #pragma unroll
              for (int reg=0;reg<4;++reg){
                const int p = rowbase + rt*16 + lg*4 + reg;
                if (p < P){
                    float gc = acc[rt][0][reg] + bgc;
                    float go = acc[rt][1][reg] + bgo;
                    float cl = sigm(gc) * C[p*st + j];
                    float hl = sigm(go) * tanhf(cl);
                    C[p*st + j] = cl;                 // overwrite left-child c in place
                    f16 hh = (f16)hl;
                    HLh[p*DH + j] = hh;
                    HLl[p*DH + j] = (f16)(hl - (float)hh);
                }
              }
            }
        }
        gbar(bar, bar+1);
        // ---- K2: parent combine. A = [h_odd | hl], task = 64 rows x (16 cols x 3 gates) ----
        for (int t = gw; t < nt; t += NWAVE){
            const int rti = t >> 4, blk = t & 15;
            const int rowbase = rti << 6;
            f32x4 acc[4][3];
            #pragma unroll
            for (int rt=0;rt<4;++rt){ f32x4 z={0.f,0.f,0.f,0.f}; acc[rt][0]=z; acc[rt][1]=z; acc[rt][2]=z; }
            int aoO[4], aoL[4];
            #pragma unroll
            for (int rt=0;rt<4;++rt){
                int p = rowbase + rt*16 + l15; p = (p < P) ? p : P-1;
                aoO[rt] = s*DH + p*st + lg*8;
                aoL[rt] = p*DH + lg*8;
            }
            const int ms0 = (blk*48 + l15)*512 + lg*8;
            const int ms1 = ms0 + 16*512;
            const int ms2 = ms1 + 16*512;
            #pragma unroll 2
            for (int kst=0; kst<8; ++kst){
                const int ko = kst*32;
                f16x8 bh0 = *(const f16x8*)(B2h + ms0 + ko);
                f16x8 bl0 = *(const f16x8*)(B2l + ms0 + ko);
                f16x8 bh1 = *(const f16x8*)(B2h + ms1 + ko);
                f16x8 bl1 = *(const f16x8*)(B2l + ms1 + ko);
                f16x8 bh2 = *(const f16x8*)(B2h + ms2 + ko);
                f16x8 bl2 = *(const f16x8*)(B2l + ms2 + ko);
                #pragma unroll
                for (int rt=0;rt<4;++rt){
                    f16x8 ah = *(const f16x8*)(Hh + aoO[rt] + ko);
                    f16x8 al = *(const f16x8*)(Hl + aoO[rt] + ko);
                    acc[rt][0] = mfma3(ah, al, bh0, bl0, acc[rt][0]);
                    acc[rt][1] = mfma3(ah, al, bh1, bl1, acc[rt][1]);
                    acc[rt][2] = mfma3(ah, al, bh2, bl2, acc[rt][2]);
                }
            }
            #pragma unroll 2
            for (int kst=0; kst<8; ++kst){
                const int ko = kst*32;
                const int kb = (kst+8)*32;
                f16x8 bh0 = *(const f16x8*)(B2h + ms0 + kb);
                f16x8 bl0 = *(const f16x8*)(B2l + ms0 + kb);
                f16x8 bh1 = *(const f16x8*)(B2h + ms1 + kb);
                f16x8 bl1 = *(const f16x8*)(B2l + ms1 + kb);
                f16x8 bh2 = *(const f16x8*)(B2h + ms2 + kb);
                f16x8 bl2 = *(const f16x8*)(B2l + ms2 + kb);
                #pragma unroll
                for (int rt=0;rt<4;++rt){
                    f16x8 ah = *(const f16x8*)(HLh + aoL[rt] + ko);
                    f16x8 al = *(const f16x8*)(HLl + aoL[rt] + ko);
                    acc[rt][0] = mfma3(ah, al, bh0, bl0, acc[rt][0]);
                    acc[rt][1] = mfma3(ah, al, bh1, bl1, acc[rt][1]);
                    acc[rt][2] = mfma3(ah, al, bh2, bl2, acc[rt][2]);
                }
            }
            const int j = blk*16 + l15;
            const float bgs = b2[blk*48 + l15];
            const float bgc = b2[blk*48 + 16 + l15];
            const float bgo = b2[blk*48 + 32 + l15];
            #pragma unroll
            for (int rt=0;rt<4;++rt){
              #pragma unroll
              for (int reg=0;reg<4;++reg){
                const int p = rowbase + rt*16 + lg*4 + reg;
                if (p < P){
                    float gs = acc[rt][0][reg] + bgs;
                    float gc = acc[rt][1][reg] + bgc;
                    float go = acc[rt][2][reg] + bgo;
                    float cn = sigm(gc)*C[s*DH + p*st + j] + sigm(gs)*C[p*st + j];
                    float hn = sigm(go)*tanhf(cn);
                    C[p*st + j] = cn;                 // parent c (same slot as cl, read above)
                    f16 hh = (f16)hn;
                    Hh[p*st + j] = hh;
                    Hl[p*st + j] = (f16)(hn - (float)hh);
                }
              }
            }
        }
        gbar(bar, bar+1);
        s <<= 1;
    }

    // ---- root: K1-type combine (sibling = 0) on node at slot 0 -> out ----
    if (gw < 16){
        const int blk = gw;
        f32x4 a0 = {0.f,0.f,0.f,0.f}, a1 = {0.f,0.f,0.f,0.f};
        const int mb0 = (blk*32 + l15)*DH + lg*8;
        const int mb1 = mb0 + 16*DH;
        for (int kst=0; kst<8; ++kst){
            const int ko = kst*32;
            f16x8 ah = *(const f16x8*)(Hh + lg*8 + ko);   // all lanes read row 0
            f16x8 al = *(const f16x8*)(Hl + lg*8 + ko);
            f16x8 bh0 = *(const f16x8*)(B1h + mb0 + ko);
            f16x8 bl0 = *(const f16x8*)(B1l + mb0 + ko);
            f16x8 bh1 = *(const f16x8*)(B1h + mb1 + ko);
            f16x8 bl1 = *(const f16x8*)(B1l + mb1 + ko);
            a0 = mfma3(ah, al, bh0, bl0, a0);
            a1 = mfma3(ah, al, bh1, bl1, a1);
        }
        if (lg == 0){
            const int j = blk*16 + l15;
            float gc = a0[0] + b1[blk*32 + l15];
            float go = a1[0] + b1[blk*32 + 16 + l15];
            float cl = sigm(gc) * C[j];
            out[j] = sigm(go) * tanhf(cl);
        }
    }
}

extern "C" void kernel_launch(void* const* d_in, const int* in_sizes, int n_in,
                              void* d_out, int out_size, void* d_ws, size_t ws_size,
                              hipStream_t stream){
    const int* wid = (const int*)d_in[0];
    const float* emb = (const float*)d_in[1];
    const float* Wx = (const float*)d_in[2];
    const float* bx = (const float*)d_in[3];
    const float* Ws = (const float*)d_in[4];
    const float* bs = (const float*)d_in[5];
    const float* Wc = (const float*)d_in[6];
    const float* bc = (const float*)d_in[7];
    float* out = (float*)d_out;

    char* p = (char*)d_ws;
    auto alloc = [&](size_t bytes){ void* r = (void*)p; p += (bytes + 255) & ~255ULL; return r; };
    int*   bar = (int*)alloc(256);
    f16*   Hh  = (f16*)alloc((size_t)NLEAF*DH*2);
    f16*   Hl  = (f16*)alloc((size_t)NLEAF*DH*2);
    float* C   = (float*)alloc((size_t)NLEAF*DH*4);
    // union region: X (leaf stage) aliased with HL (tree stage)
    char*  U   = (char*)alloc((size_t)NLEAF*KL*2*2);
    f16*   Xh  = (f16*)U;
    f16*   Xl  = (f16*)(U + (size_t)NLEAF*KL*2);
    f16*   HLh = (f16*)U;
    f16*   HLl = (f16*)(U + (size_t)(NLEAF/2)*DH*2);
    f16* BLh = (f16*)alloc((size_t)G3*KL*2); f16* BLl = (f16*)alloc((size_t)G3*KL*2);
    f16* B1h = (f16*)alloc((size_t)512*DH*2); f16* B1l = (f16*)alloc((size_t)512*DH*2);
    f16* B2h = (f16*)alloc((size_t)G3*512*2); f16* B2l = (f16*)alloc((size_t)G3*512*2);
    float* bL = (float*)alloc(G3*4);
    float* b1 = (float*)alloc(512*4);
    float* b2 = (float*)alloc(G3*4);

    const int nprep = G3*KL + 512*DH + G3*512 + G3 + 512 + G3;
    prep_kernel<<<(nprep+255)/256, 256, 0, stream>>>(Wx,Wc,Ws,bx,bs,bc,
        BLh,BLl,B1h,B1l,B2h,B2l,bL,b1,b2,bar);
    gather_kernel<<<(NLEAF*KL)/256, 256, 0, stream>>>(wid, emb, Xh, Xl);
    leaf_kernel<<<dim3(NLEAF/64, 4), 256, 0, stream>>>(Xh, Xl, BLh, BLl, bL, Hh, Hl, C);
    tree_kernel<<<NBLK, NTHR, 0, stream>>>(Hh, Hl, C, HLh, HLl,
        B1h, B1l, B2h, B2l, b1, b2, out, bar);
}

// Round 7
// 1725.044 us; speedup vs baseline: 3.4211x; 3.4211x over previous
//
#include <hip/hip_runtime.h>
#include <cmath>

typedef _Float16 f16;
typedef _Float16 f16x8 __attribute__((ext_vector_type(8)));
typedef float f32x4 __attribute__((ext_vector_type(4)));

#define DH 256
#define G3 768
#define DIN 300
#define KL 320
#define NLEAF 16384
#define LPAD 264   // LDS row pitch (f16 elems): 528B rows -> r and r+8 alias (2-way, free)

__device__ __forceinline__ float sigm(float x){ return 1.0f/(1.0f+expf(-x)); }

__device__ __forceinline__ f32x4 mfma3(f16x8 ah, f16x8 al, f16x8 bh, f16x8 bl, f32x4 acc){
    acc = __builtin_amdgcn_mfma_f32_16x16x32_f16(ah, bh, acc, 0,0,0);
    acc = __builtin_amdgcn_mfma_f32_16x16x32_f16(ah, bl, acc, 0,0,0);
    acc = __builtin_amdgcn_mfma_f32_16x16x32_f16(al, bh, acc, 0,0,0);
    return acc;
}

// ---- prep1: weight transpose/split to MFMA-friendly [m][k] rows ----
__global__ void prep_kernel(const float* __restrict__ Wx, const float* __restrict__ Wc,
                            const float* __restrict__ Ws, const float* __restrict__ bx,
                            const float* __restrict__ bs, const float* __restrict__ bc,
                            f16* __restrict__ BLh, f16* __restrict__ BLl,
                            f16* __restrict__ B1h, f16* __restrict__ B1l,
                            f16* __restrict__ B2h, f16* __restrict__ B2l,
                            float* __restrict__ bL, float* __restrict__ b1, float* __restrict__ b2){
    int idx = blockIdx.x*256 + threadIdx.x;
    const int nBL = G3*KL, nB1 = 512*DH, nB2 = G3*512;
    if (idx < nBL){
        int m = idx / KL, k = idx - m*KL;
        int blk = m/48, rem = m - blk*48, g = rem>>4, j = blk*16 + (rem&15);
        float v = (k < DIN) ? Wx[k*G3 + g*DH + j] : 0.0f;
        f16 h = (f16)v; BLh[idx] = h; BLl[idx] = (f16)(v - (float)h);
        return;
    }
    idx -= nBL;
    if (idx < nB1){
        int m = idx >> 8, k = idx & 255;
        int blk = m>>5, rem = m & 31, gg = rem>>4, j = blk*16 + (rem&15);
        float v = Wc[k*G3 + (gg+1)*DH + j];
        f16 h = (f16)v; B1h[idx] = h; B1l[idx] = (f16)(v - (float)h);
        return;
    }
    idx -= nB1;
    if (idx < nB2){
        int m = idx >> 9, k = idx & 511;
        int blk = m/48, rem = m - blk*48, g = rem>>4, j = blk*16 + (rem&15);
        float v = (k < DH) ? Wc[k*G3 + g*DH + j] : Ws[(k-DH)*G3 + g*DH + j];
        f16 h = (f16)v; B2h[idx] = h; B2l[idx] = (f16)(v - (float)h);
        return;
    }
    idx -= nB2;
    if (idx < G3){
        int blk = idx/48, rem = idx - blk*48, g = rem>>4, j = blk*16 + (rem&15);
        bL[idx] = bx[g*DH + j]; return;
    }
    idx -= G3;
    if (idx < 512){
        int blk = idx>>5, rem = idx & 31, gg = rem>>4, j = blk*16 + (rem&15);
        b1[idx] = bc[(gg+1)*DH+j] + bs[(gg+1)*DH+j]; return;
    }
    idx -= 512;
    if (idx < G3){
        int blk = idx/48, rem = idx - blk*48, g = rem>>4, j = blk*16 + (rem&15);
        b2[idx] = bc[g*DH+j] + bs[g*DH+j];
    }
}

// ---- prep2: gather leaf embedding rows, pre-split to f16 hi/lo ----
__global__ void gather_kernel(const int* __restrict__ wid, const float* __restrict__ emb,
                              f16* __restrict__ Xh, f16* __restrict__ Xl){
    int idx = blockIdx.x*256 + threadIdx.x;        // over NLEAF*KL
    int r = idx / KL, k = idx - r*KL;
    float v = (k < DIN) ? emb[wid[r]*DIN + k] : 0.0f;
    f16 h = (f16)v;
    Xh[idx] = h; Xl[idx] = (f16)(v - (float)h);
}

// ---- leaf: pure split-f16 MFMA GEMM [16384 x 320] @ BL -> gated h,c ----
__global__ __launch_bounds__(256) void leaf_kernel(
    const f16* __restrict__ Xh, const f16* __restrict__ Xl,
    const f16* __restrict__ BLh, const f16* __restrict__ BLl, const float* __restrict__ bL,
    f16* __restrict__ Hh, f16* __restrict__ Hl, float* __restrict__ C)
{
    const int tid = threadIdx.x;
    const int lane = tid & 63, w = tid >> 6;
    const int cg = blockIdx.y*4 + w;               // 0..15
    const int l15 = lane & 15, lg = lane >> 4;
    const int rowbase = blockIdx.x * 64;

    f32x4 acc[4][3];
    #pragma unroll
    for (int rt=0;rt<4;++rt)
      #pragma unroll
      for (int g=0;g<3;++g){ f32x4 z={0.f,0.f,0.f,0.f}; acc[rt][g]=z; }

    int ax[4];
    #pragma unroll
    for (int rt=0;rt<4;++rt) ax[rt] = (rowbase + rt*16 + l15)*KL + lg*8;
    const int m0 = (cg*48 + l15)*KL + lg*8;
    const int m1 = m0 + 16*KL;
    const int m2 = m1 + 16*KL;

    #pragma unroll 2
    for (int kst=0; kst<10; ++kst){
        const int ko = kst*32;
        f16x8 bh0 = *(const f16x8*)(BLh + m0 + ko);
        f16x8 bl0 = *(const f16x8*)(BLl + m0 + ko);
        f16x8 bh1 = *(const f16x8*)(BLh + m1 + ko);
        f16x8 bl1 = *(const f16x8*)(BLl + m1 + ko);
        f16x8 bh2 = *(const f16x8*)(BLh + m2 + ko);
        f16x8 bl2 = *(const f16x8*)(BLl + m2 + ko);
        #pragma unroll
        for (int rt=0;rt<4;++rt){
            f16x8 ah = *(const f16x8*)(Xh + ax[rt] + ko);
            f16x8 al = *(const f16x8*)(Xl + ax[rt] + ko);
            acc[rt][0] = mfma3(ah, al, bh0, bl0, acc[rt][0]);
            acc[rt][1] = mfma3(ah, al, bh1, bl1, acc[rt][1]);
            acc[rt][2] = mfma3(ah, al, bh2, bl2, acc[rt][2]);
        }
    }
    const int j = cg*16 + l15;
    const float bv0 = bL[cg*48 + l15];
    const float bv1 = bL[cg*48 + 16 + l15];
    const float bv2 = bL[cg*48 + 32 + l15];
    #pragma unroll
    for (int rt=0;rt<4;++rt){
      #pragma unroll
      for (int reg=0;reg<4;++reg){
        const int r = rowbase + rt*16 + lg*4 + reg;
        float gi = acc[rt][0][reg] + bv0;
        float go = acc[rt][1][reg] + bv1;
        float cp = acc[rt][2][reg] + bv2;
        float c = sigm(gi)*tanhf(cp);
        float h = sigm(go)*tanhf(c);
        C[r*DH + j] = c;
        f16 hh = (f16)h;
        Hh[r*DH + j] = hh;
        Hl[r*DH + j] = (f16)(h - (float)hh);
      }
    }
}

// ---- fused level: each block = ROWS parents x all 768 cols. K1 -> LDS/regs, K2.
// Wave w handles col-groups {w, w+8}. No grid sync: one launch per level.
template<int RT, int MINW>
__global__ __launch_bounds__(512, MINW) void level_kernel(
    f16* __restrict__ Hh, f16* __restrict__ Hl, float* __restrict__ C,
    const f16* __restrict__ B1h, const f16* __restrict__ B1l,
    const f16* __restrict__ B2h, const f16* __restrict__ B2l,
    const float* __restrict__ b1, const float* __restrict__ b2,
    const int s, const int P)
{
    constexpr int ROWS = RT*16;
    __shared__ __align__(16) f16 SHh[ROWS][LPAD];
    __shared__ __align__(16) f16 SHl[ROWS][LPAD];
    const int tid = threadIdx.x;
    const int w = tid >> 6, lane = tid & 63, l15 = lane & 15, lg = lane >> 4;
    const int pbase = blockIdx.x * ROWS;
    const int st = 2*s*DH;

    float clr[2][RT][4];

    // ---- K1: left-combine (gates gc, go), hl -> LDS, cl -> regs ----
    #pragma unroll
    for (int gi=0; gi<2; ++gi){
        const int blk = w + gi*8;
        f32x4 acc[RT][2];
        #pragma unroll
        for (int rt=0;rt<RT;++rt){ f32x4 z={0.f,0.f,0.f,0.f}; acc[rt][0]=z; acc[rt][1]=z; }
        int ao[RT];
        #pragma unroll
        for (int rt=0;rt<RT;++rt){
            int p = pbase + rt*16 + l15; p = (p < P) ? p : P-1;
            ao[rt] = p*st + lg*8;                       // left child h (slot p*st)
        }
        const int mb0 = (blk*32 + l15)*DH + lg*8;
        const int mb1 = mb0 + 16*DH;
        #pragma unroll 2
        for (int kst=0; kst<8; ++kst){
            const int ko = kst*32;
            f16x8 bh0 = *(const f16x8*)(B1h + mb0 + ko);
            f16x8 bl0 = *(const f16x8*)(B1l + mb0 + ko);
            f16x8 bh1 = *(const f16x8*)(B1h + mb1 + ko);
            f16x8 bl1 = *(const f16x8*)(B1l + mb1 + ko);
            #pragma unroll
            for (int rt=0;rt<RT;++rt){
                if (rt*16 < P){
                    f16x8 ah = *(const f16x8*)(Hh + ao[rt] + ko);
                    f16x8 al = *(const f16x8*)(Hl + ao[rt] + ko);
                    acc[rt][0] = mfma3(ah, al, bh0, bl0, acc[rt][0]);
                    acc[rt][1] = mfma3(ah, al, bh1, bl1, acc[rt][1]);
                }
            }
        }
        const int j = blk*16 + l15;
        const float bgc = b1[blk*32 + l15];
        const float bgo = b1[blk*32 + 16 + l15];
        #pragma unroll
        for (int rt=0;rt<RT;++rt){
          if (rt*16 < P){
            #pragma unroll
            for (int reg=0;reg<4;++reg){
                const int r = rt*16 + lg*4 + reg;
                int p = pbase + r; p = (p < P) ? p : P-1;
                float gc = acc[rt][0][reg] + bgc;
                float go = acc[rt][1][reg] + bgo;
                float cl = sigm(gc) * C[p*st + j];
                float hl = sigm(go) * tanhf(cl);
                clr[gi][rt][reg] = cl;
                f16 hh = (f16)hl;
                SHh[r][j] = hh;
                SHl[r][j] = (f16)(hl - (float)hh);
            }
          }
        }
    }
    __syncthreads();
    // ---- K2: parent combine. A = [h_odd(global) | hl(LDS)] ----
    #pragma unroll
    for (int gi=0; gi<2; ++gi){
        const int blk = w + gi*8;
        f32x4 acc[RT][3];
        #pragma unroll
        for (int rt=0;rt<RT;++rt){ f32x4 z={0.f,0.f,0.f,0.f}; acc[rt][0]=z; acc[rt][1]=z; acc[rt][2]=z; }
        int aoO[RT];
        #pragma unroll
        for (int rt=0;rt<RT;++rt){
            int p = pbase + rt*16 + l15; p = (p < P) ? p : P-1;
            aoO[rt] = s*DH + p*st + lg*8;               // right child h
        }
        const int ms0 = (blk*48 + l15)*512 + lg*8;
        const int ms1 = ms0 + 16*512;
        const int ms2 = ms1 + 16*512;
        #pragma unroll 2
        for (int kst=0; kst<8; ++kst){
            const int ko = kst*32;
            f16x8 bh0 = *(const f16x8*)(B2h + ms0 + ko);
            f16x8 bl0 = *(const f16x8*)(B2l + ms0 + ko);
            f16x8 bh1 = *(const f16x8*)(B2h + ms1 + ko);
            f16x8 bl1 = *(const f16x8*)(B2l + ms1 + ko);
            f16x8 bh2 = *(const f16x8*)(B2h + ms2 + ko);
            f16x8 bl2 = *(const f16x8*)(B2l + ms2 + ko);
            #pragma unroll
            for (int rt=0;rt<RT;++rt){
                if (rt*16 < P){
                    f16x8 ah = *(const f16x8*)(Hh + aoO[rt] + ko);
                    f16x8 al = *(const f16x8*)(Hl + aoO[rt] + ko);
                    acc[rt][0] = mfma3(ah, al, bh0, bl0, acc[rt][0]);
                    acc[rt][1] = mfma3(ah, al, bh1, bl1, acc[rt][1]);
                    acc[rt][2] = mfma3(ah, al, bh2, bl2, acc[rt][2]);
                }
            }
        }
        #pragma unroll 2
        for (int kst=0; kst<8; ++kst){
            const int ko = kst*32;
            const int kb = (kst+8)*32;
            f16x8 bh0 = *(const f16x8*)(B2h + ms0 + kb);
            f16x8 bl0 = *(const f16x8*)(B2l + ms0 + kb);
            f16x8 bh1 = *(const f16x8*)(B2h + ms1 + kb);
            f16x8 bl1 = *(const f16x8*)(B2l + ms1 + kb);
            f16x8 bh2 = *(const f16x8*)(B2h + ms2 + kb);
            f16x8 bl2 = *(const f16x8*)(B2l + ms2 + kb);
            #pragma unroll
            for (int rt=0;rt<RT;++rt){
                if (rt*16 < P){
                    const int r2 = rt*16 + l15;
                    f16x8 ah = *(const f16x8*)&SHh[r2][ko + lg*8];
                    f16x8 al = *(const f16x8*)&SHl[r2][ko + lg*8];
                    acc[rt][0] = mfma3(ah, al, bh0, bl0, acc[rt][0]);
                    acc[rt][1] = mfma3(ah, al, bh1, bl1, acc[rt][1]);
                    acc[rt][2] = mfma3(ah, al, bh2, bl2, acc[rt][2]);
                }
            }
        }
        const int j = blk*16 + l15;
        const float bgs = b2[blk*48 + l15];
        const float bgc = b2[blk*48 + 16 + l15];
        const float bgo = b2[blk*48 + 32 + l15];
        #pragma unroll
        for (int rt=0;rt<RT;++rt){
          #pragma unroll
          for (int reg=0;reg<4;++reg){
            const int p = pbase + rt*16 + lg*4 + reg;
            if (p < P){
                float gs = acc[rt][0][reg] + bgs;
                float gc = acc[rt][1][reg] + bgc;
                float go = acc[rt][2][reg] + bgo;
                float cn = sigm(gc)*C[s*DH + p*st + j] + sigm(gs)*clr[gi][rt][reg];
                float hn = sigm(go)*tanhf(cn);
                C[p*st + j] = cn;
                f16 hh = (f16)hn;
                Hh[p*st + j] = hh;
                Hl[p*st + j] = (f16)(hn - (float)hh);
            }
          }
        }
    }
}

// ---- tail: single block walks P=64..1 (+root) with block-local syncs ----
__global__ __launch_bounds__(512, 2) void tail_kernel(
    f16* __restrict__ Hh, f16* __restrict__ Hl, float* __restrict__ C,
    const f16* __restrict__ B1h, const f16* __restrict__ B1l,
    const f16* __restrict__ B2h, const f16* __restrict__ B2l,
    const float* __restrict__ b1, const float* __restrict__ b2,
    float* __restrict__ out)
{
    __shared__ __align__(16) f16 SHh[64][LPAD];
    __shared__ __align__(16) f16 SHl[64][LPAD];
    const int tid = threadIdx.x;
    const int w = tid >> 6, lane = tid & 63, l15 = lane & 15, lg = lane >> 4;

    float clr[2][4][4];

    int s = 128;
    for (int P = 64; P >= 1; P >>= 1, s <<= 1){
        const int st = 2*s*DH;
        // K1
        #pragma unroll
        for (int gi=0; gi<2; ++gi){
            const int blk = w + gi*8;
            f32x4 acc[4][2];
            #pragma unroll
            for (int rt=0;rt<4;++rt){ f32x4 z={0.f,0.f,0.f,0.f}; acc[rt][0]=z; acc[rt][1]=z; }
            int ao[4];
            #pragma unroll
            for (int rt=0;rt<4;++rt){
                int p = rt*16 + l15; p = (p < P) ? p : P-1;
                ao[rt] = p*st + lg*8;
            }
            const int mb0 = (blk*32 + l15)*DH + lg*8;
            const int mb1 = mb0 + 16*DH;
            for (int kst=0; kst<8; ++kst){
                const int ko = kst*32;
                f16x8 bh0 = *(const f16x8*)(B1h + mb0 + ko);
                f16x8 bl0 = *(const f16x8*)(B1l + mb0 + ko);
                f16x8 bh1 = *(const f16x8*)(B1h + mb1 + ko);
                f16x8 bl1 = *(const f16x8*)(B1l + mb1 + ko);
                #pragma unroll
                for (int rt=0;rt<4;++rt){
                    if (rt*16 < P){
                        f16x8 ah = *(const f16x8*)(Hh + ao[rt] + ko);
                        f16x8 al = *(const f16x8*)(Hl + ao[rt] + ko);
                        acc[rt][0] = mfma3(ah, al, bh0, bl0, acc[rt][0]);
                        acc[rt][1] = mfma3(ah, al, bh1, bl1, acc[rt][1]);
                    }
                }
            }
            const int j = blk*16 + l15;
            const float bgc = b1[blk*32 + l15];
            const float bgo = b1[blk*32 + 16 + l15];
            #pragma unroll
            for (int rt=0;rt<4;++rt){
              if (rt*16 < P){
                #pragma unroll
                for (int reg=0;reg<4;++reg){
                    const int r = rt*16 + lg*4 + reg;
                    int p = r; p = (p < P) ? p : P-1;
                    float gc = acc[rt][0][reg] + bgc;
                    float go = acc[rt][1][reg] + bgo;
                    float cl = sigm(gc) * C[p*st + j];
                    float hl = sigm(go) * tanhf(cl);
                    clr[gi][rt][reg] = cl;
                    f16 hh = (f16)hl;
                    SHh[r][j] = hh;
                    SHl[r][j] = (f16)(hl - (float)hh);
                }
              }
            }
        }
        __syncthreads();
        // K2
        #pragma unroll
        for (int gi=0; gi<2; ++gi){
            const int blk = w + gi*8;
            f32x4 acc[4][3];
            #pragma unroll
            for (int rt=0;rt<4;++rt){ f32x4 z={0.f,0.f,0.f,0.f}; acc[rt][0]=z; acc[rt][1]=z; acc[rt][2]=z; }
            int aoO[4];
            #pragma unroll
            for (int rt=0;rt<4;++rt){
                int p = rt*16 + l15; p = (p < P) ? p : P-1;
                aoO[rt] = s*DH + p*st + lg*8;
            }
            const int ms0 = (blk*48 + l15)*512 + lg*8;
            const int ms1 = ms0 + 16*512;
            const int ms2 = ms1 + 16*512;
            for (int kst=0; kst<8; ++kst){
                const int ko = kst*32;
                f16x8 bh0 = *(const f16x8*)(B2h + ms0 + ko);
                f16x8 bl0 = *(const f16x8*)(B2l + ms0 + ko);
                f16x8 bh1 = *(const f16x8*)(B2h + ms1 + ko);
                f16x8 bl1 = *(const f16x8*)(B2l + ms1 + ko);
                f16x8 bh2 = *(const f16x8*)(B2h + ms2 + ko);
                f16x8 bl2 = *(const f16x8*)(B2l + ms2 + ko);
                #pragma unroll
                for (int rt=0;rt<4;++rt){
                    if (rt*16 < P){
                        f16x8 ah = *(const f16x8*)(Hh + aoO[rt] + ko);
                        f16x8 al = *(const f16x8*)(Hl + aoO[rt] + ko);
                        acc[rt][0] = mfma3(ah, al, bh0, bl0, acc[rt][0]);
                        acc[rt][1] = mfma3(ah, al, bh1, bl1, acc[rt][1]);
                        acc[rt][2] = mfma3(ah, al, bh2, bl2, acc[rt][2]);
                    }
                }
            }
            for (int kst=0; kst<8; ++kst){
                const int ko = kst*32;
                const int kb = (kst+8)*32;
                f16x8 bh0 = *(const f16x8*)(B2h + ms0 + kb);
                f16x8 bl0 = *(const f16x8*)(B2l + ms0 + kb);
                f16x8 bh1 = *(const f16x8*)(B2h + ms1 + kb);
                f16x8 bl1 = *(const f16x8*)(B2l + ms1 + kb);
                f16x8 bh2 = *(const f16x8*)(B2h + ms2 + kb);
                f16x8 bl2 = *(const f16x8*)(B2l + ms2 + kb);
                #pragma unroll
                for (int rt=0;rt<4;++rt){
                    if (rt*16 < P){
                        const int r2 = rt*16 + l15;
                        f16x8 ah = *(const f16x8*)&SHh[r2][ko + lg*8];
                        f16x8 al = *(const f16x8*)&SHl[r2][ko + lg*8];
                        acc[rt][0] = mfma3(ah, al, bh0, bl0, acc[rt][0]);
                        acc[rt][1] = mfma3(ah, al, bh1, bl1, acc[rt][1]);
                        acc[rt][2] = mfma3(ah, al, bh2, bl2, acc[rt][2]);
                    }
                }
            }
            const int j = blk*16 + l15;
            const float bgs = b2[blk*48 + l15];
            const float bgc = b2[blk*48 + 16 + l15];
            const float bgo = b2[blk*48 + 32 + l15];
            #pragma unroll
            for (int rt=0;rt<4;++rt){
              #pragma unroll
              for (int reg=0;reg<4;++reg){
                const int p = rt*16 + lg*4 + reg;
                if (p < P){
                    float gs = acc[rt][0][reg] + bgs;
                    float gc = acc[rt][1][reg] + bgc;
                    float go = acc[rt][2][reg] + bgo;
                    float cn = sigm(gc)*C[s*DH + p*st + j] + sigm(gs)*clr[gi][rt][reg];
                    float hn = sigm(go)*tanhf(cn);
                    C[p*st + j] = cn;
                    f16 hh = (f16)hn;
                    Hh[p*st + j] = hh;
                    Hl[p*st + j] = (f16)(hn - (float)hh);
                }
              }
            }
        }
        __syncthreads();
    }

    // root: K1-type combine (sibling = 0) on node at slot 0 -> out
    #pragma unroll
    for (int gi=0; gi<2; ++gi){
        const int blk = w + gi*8;
        f32x4 a0 = {0.f,0.f,0.f,0.f}, a1 = {0.f,0.f,0.f,0.f};
        const int mb0 = (blk*32 + l15)*DH + lg*8;
        const int mb1 = mb0 + 16*DH;
        for (int kst=0; kst<8; ++kst){
            const int ko = kst*32;
            f16x8 ah = *(const f16x8*)(Hh + lg*8 + ko);
            f16x8 al = *(const f16x8*)(Hl + lg*8 + ko);
            f16x8 bh0 = *(const f16x8*)(B1h + mb0 + ko);
            f16x8 bl0 = *(const f16x8*)(B1l + mb0 + ko);
            f16x8 bh1 = *(const f16x8*)(B1h + mb1 + ko);
            f16x8 bl1 = *(const f16x8*)(B1l + mb1 + ko);
            a0 = mfma3(ah, al, bh0, bl0, a0);
            a1 = mfma3(ah, al, bh1, bl1, a1);
        }
        if (lg == 0){
            const int j = blk*16 + l15;
            float gc = a0[0] + b1[blk*32 + l15];
            float go = a1[0] + b1[blk*32 + 16 + l15];
            float cl = sigm(gc) * C[j];
            out[j] = sigm(go) * tanhf(cl);
        }
    }
}

extern "C" void kernel_launch(void* const* d_in, const int* in_sizes, int n_in,
                              void* d_out, int out_size, void* d_ws, size_t ws_size,
                              hipStream_t stream){
    const int* wid = (const int*)d_in[0];
    const float* emb = (const float*)d_in[1];
    const float* Wx = (const float*)d_in[2];
    const float* bx = (const float*)d_in[3];
    const float* Ws = (const float*)d_in[4];
    const float* bs = (const float*)d_in[5];
    const float* Wc = (const float*)d_in[6];
    const float* bc = (const float*)d_in[7];
    float* out = (float*)d_out;

    char* p = (char*)d_ws;
    auto alloc = [&](size_t bytes){ void* r = (void*)p; p += (bytes + 255) & ~255ULL; return r; };
    f16*   Hh  = (f16*)alloc((size_t)NLEAF*DH*2);
    f16*   Hl  = (f16*)alloc((size_t)NLEAF*DH*2);
    float* C   = (float*)alloc((size_t)NLEAF*DH*4);
    f16*   Xh  = (f16*)alloc((size_t)NLEAF*KL*2);
    f16*   Xl  = (f16*)alloc((size_t)NLEAF*KL*2);
    f16* BLh = (f16*)alloc((size_t)G3*KL*2); f16* BLl = (f16*)alloc((size_t)G3*KL*2);
    f16* B1h = (f16*)alloc((size_t)512*DH*2); f16* B1l = (f16*)alloc((size_t)512*DH*2);
    f16* B2h = (f16*)alloc((size_t)G3*512*2); f16* B2l = (f16*)alloc((size_t)G3*512*2);
    float* bL = (float*)alloc(G3*4);
    float* b1 = (float*)alloc(512*4);
    float* b2 = (float*)alloc(G3*4);

    const int nprep = G3*KL + 512*DH + G3*512 + G3 + 512 + G3;
    prep_kernel<<<(nprep+255)/256, 256, 0, stream>>>(Wx,Wc,Ws,bx,bs,bc,
        BLh,BLl,B1h,B1l,B2h,B2l,bL,b1,b2);
    gather_kernel<<<(NLEAF*KL)/256, 256, 0, stream>>>(wid, emb, Xh, Xl);
    leaf_kernel<<<dim3(NLEAF/64, 4), 256, 0, stream>>>(Xh, Xl, BLh, BLl, bL, Hh, Hl, C);

    int s = 1;
    for (int P = NLEAF/2; P >= 128; P >>= 1){
        if (P >= 4096){
            level_kernel<4,2><<<P/64, 512, 0, stream>>>(Hh,Hl,C, B1h,B1l,B2h,B2l, b1,b2, s,P);
        } else {
            level_kernel<2,4><<<P/32, 512, 0, stream>>>(Hh,Hl,C, B1h,B1l,B2h,B2l, b1,b2, s,P);
        }
        s <<= 1;
    }
    tail_kernel<<<1, 512, 0, stream>>>(Hh,Hl,C, B1h,B1l,B2h,B2l, b1,b2, out);
}

// Round 8
// 697.397 us; speedup vs baseline: 8.4623x; 2.4735x over previous
//
#include <hip/hip_runtime.h>
#include <cmath>

typedef _Float16 f16;
typedef _Float16 f16x8 __attribute__((ext_vector_type(8)));
typedef float f32x4 __attribute__((ext_vector_type(4)));

#define DH 256
#define G3 768
#define DIN 300
#define KL 320
#define NLEAF 16384
#define PNB 16          // persistent-kernel block count (1 col-group each)

__device__ __forceinline__ float sigm(float x){ return 1.0f/(1.0f+expf(-x)); }

__device__ __forceinline__ f32x4 mfma3(f16x8 ah, f16x8 al, f16x8 bh, f16x8 bl, f32x4 acc){
    acc = __builtin_amdgcn_mfma_f32_16x16x32_f16(ah, bh, acc, 0,0,0);
    acc = __builtin_amdgcn_mfma_f32_16x16x32_f16(ah, bl, acc, 0,0,0);
    acc = __builtin_amdgcn_mfma_f32_16x16x32_f16(al, bh, acc, 0,0,0);
    return acc;
}

// Device-scope grid barrier (PNB blocks, all trivially co-resident).
__device__ __forceinline__ void gbar(int* cnt, int* gen){
    __syncthreads();
    if (threadIdx.x == 0){
        __threadfence();
        int g = __hip_atomic_load(gen, __ATOMIC_RELAXED, __HIP_MEMORY_SCOPE_AGENT);
        int old = __hip_atomic_fetch_add(cnt, 1, __ATOMIC_ACQ_REL, __HIP_MEMORY_SCOPE_AGENT);
        if (old == PNB-1){
            __hip_atomic_store(cnt, 0, __ATOMIC_RELAXED, __HIP_MEMORY_SCOPE_AGENT);
            __hip_atomic_store(gen, g+1, __ATOMIC_RELEASE, __HIP_MEMORY_SCOPE_AGENT);
        } else {
            while (__hip_atomic_load(gen, __ATOMIC_ACQUIRE, __HIP_MEMORY_SCOPE_AGENT) == g)
                __builtin_amdgcn_s_sleep(2);
        }
        __threadfence();
    }
    __syncthreads();
}

// ---- prep1: weight transpose/split to MFMA row-major [m][k] + bar init ----
__global__ void prep_kernel(const float* __restrict__ Wx, const float* __restrict__ Wc,
                            const float* __restrict__ Ws, const float* __restrict__ bx,
                            const float* __restrict__ bs, const float* __restrict__ bc,
                            f16* __restrict__ BLh, f16* __restrict__ BLl,
                            f16* __restrict__ B1h, f16* __restrict__ B1l,
                            f16* __restrict__ B2h, f16* __restrict__ B2l,
                            float* __restrict__ bL, float* __restrict__ b1, float* __restrict__ b2,
                            int* __restrict__ bar){
    if (blockIdx.x == 0 && threadIdx.x == 0){ bar[0] = 0; bar[1] = 0; }
    int idx = blockIdx.x*256 + threadIdx.x;
    const int nBL = G3*KL, nB1 = 512*DH, nB2 = G3*512;
    if (idx < nBL){
        int m = idx / KL, k = idx - m*KL;
        int blk = m/48, rem = m - blk*48, g = rem>>4, j = blk*16 + (rem&15);
        float v = (k < DIN) ? Wx[k*G3 + g*DH + j] : 0.0f;
        f16 h = (f16)v; BLh[idx] = h; BLl[idx] = (f16)(v - (float)h);
        return;
    }
    idx -= nBL;
    if (idx < nB1){
        int m = idx >> 8, k = idx & 255;
        int blk = m>>5, rem = m & 31, gg = rem>>4, j = blk*16 + (rem&15);
        float v = Wc[k*G3 + (gg+1)*DH + j];
        f16 h = (f16)v; B1h[idx] = h; B1l[idx] = (f16)(v - (float)h);
        return;
    }
    idx -= nB1;
    if (idx < nB2){
        int m = idx >> 9, k = idx & 511;
        int blk = m/48, rem = m - blk*48, g = rem>>4, j = blk*16 + (rem&15);
        float v = (k < DH) ? Wc[k*G3 + g*DH + j] : Ws[(k-DH)*G3 + g*DH + j];
        f16 h = (f16)v; B2h[idx] = h; B2l[idx] = (f16)(v - (float)h);
        return;
    }
    idx -= nB2;
    if (idx < G3){
        int blk = idx/48, rem = idx - blk*48, g = rem>>4, j = blk*16 + (rem&15);
        bL[idx] = bx[g*DH + j]; return;
    }
    idx -= G3;
    if (idx < 512){
        int blk = idx>>5, rem = idx & 31, gg = rem>>4, j = blk*16 + (rem&15);
        b1[idx] = bc[(gg+1)*DH+j] + bs[(gg+1)*DH+j]; return;
    }
    idx -= 512;
    if (idx < G3){
        int blk = idx/48, rem = idx - blk*48, g = rem>>4, j = blk*16 + (rem&15);
        b2[idx] = bc[g*DH+j] + bs[g*DH+j];
    }
}

// ---- prep2: gather leaf embedding rows, pre-split to f16 hi/lo ----
__global__ void gather_kernel(const int* __restrict__ wid, const float* __restrict__ emb,
                              f16* __restrict__ Xh, f16* __restrict__ Xl){
    int idx = blockIdx.x*256 + threadIdx.x;        // over NLEAF*KL
    int r = idx / KL, k = idx - r*KL;
    float v = (k < DIN) ? emb[wid[r]*DIN + k] : 0.0f;
    f16 h = (f16)v;
    Xh[idx] = h; Xl[idx] = (f16)(v - (float)h);
}

// ---- leaf: pure split-f16 MFMA GEMM [16384 x 320] @ BL -> gated h,c ----
__global__ __launch_bounds__(256) void leaf_kernel(
    const f16* __restrict__ Xh, const f16* __restrict__ Xl,
    const f16* __restrict__ BLh, const f16* __restrict__ BLl, const float* __restrict__ bL,
    f16* __restrict__ Hh, f16* __restrict__ Hl, float* __restrict__ C)
{
    const int tid = threadIdx.x;
    const int lane = tid & 63, w = tid >> 6;
    const int cg = blockIdx.y*4 + w;               // 0..15
    const int l15 = lane & 15, lg = lane >> 4;
    const int rowbase = blockIdx.x * 64;

    f32x4 acc[4][3];
    #pragma unroll
    for (int rt=0;rt<4;++rt)
      #pragma unroll
      for (int g=0;g<3;++g){ f32x4 z={0.f,0.f,0.f,0.f}; acc[rt][g]=z; }

    int ax[4];
    #pragma unroll
    for (int rt=0;rt<4;++rt) ax[rt] = (rowbase + rt*16 + l15)*KL + lg*8;
    const int m0 = (cg*48 + l15)*KL + lg*8;
    const int m1 = m0 + 16*KL;
    const int m2 = m1 + 16*KL;

    #pragma unroll 2
    for (int kst=0; kst<10; ++kst){
        const int ko = kst*32;
        f16x8 bh0 = *(const f16x8*)(BLh + m0 + ko);
        f16x8 bl0 = *(const f16x8*)(BLl + m0 + ko);
        f16x8 bh1 = *(const f16x8*)(BLh + m1 + ko);
        f16x8 bl1 = *(const f16x8*)(BLl + m1 + ko);
        f16x8 bh2 = *(const f16x8*)(BLh + m2 + ko);
        f16x8 bl2 = *(const f16x8*)(BLl + m2 + ko);
        #pragma unroll
        for (int rt=0;rt<4;++rt){
            f16x8 ah = *(const f16x8*)(Xh + ax[rt] + ko);
            f16x8 al = *(const f16x8*)(Xl + ax[rt] + ko);
            acc[rt][0] = mfma3(ah, al, bh0, bl0, acc[rt][0]);
            acc[rt][1] = mfma3(ah, al, bh1, bl1, acc[rt][1]);
            acc[rt][2] = mfma3(ah, al, bh2, bl2, acc[rt][2]);
        }
    }
    const int j = cg*16 + l15;
    const float bv0 = bL[cg*48 + l15];
    const float bv1 = bL[cg*48 + 16 + l15];
    const float bv2 = bL[cg*48 + 32 + l15];
    #pragma unroll
    for (int rt=0;rt<4;++rt){
      #pragma unroll
      for (int reg=0;reg<4;++reg){
        const int r = rowbase + rt*16 + lg*4 + reg;
        float gi = acc[rt][0][reg] + bv0;
        float go = acc[rt][1][reg] + bv1;
        float cp = acc[rt][2][reg] + bv2;
        float c = sigm(gi)*tanhf(cp);
        float h = sigm(go)*tanhf(c);
        C[r*DH + j] = c;
        f16 hh = (f16)h;
        Hh[r*DH + j] = hh;
        Hl[r*DH + j] = (f16)(h - (float)hh);
      }
    }
}

// ---- big-level K1: left-combine. grid (P/64, 4), 4 waves x 16 col-groups ----
__global__ __launch_bounds__(256) void k1_kernel(
    const f16* __restrict__ Hh, const f16* __restrict__ Hl, float* __restrict__ C,
    const f16* __restrict__ B1h, const f16* __restrict__ B1l, const float* __restrict__ b1,
    f16* __restrict__ HLh, f16* __restrict__ HLl, const int s, const int P)
{
    const int tid = threadIdx.x, lane = tid & 63, w = tid >> 6;
    const int cg = blockIdx.y*4 + w;
    const int l15 = lane & 15, lg = lane >> 4;
    const int rowbase = blockIdx.x * 64;
    const int st = 2*s*DH;

    f32x4 a0[4], a1[4];
    #pragma unroll
    for (int rt=0;rt<4;++rt){ f32x4 z={0.f,0.f,0.f,0.f}; a0[rt]=z; a1[rt]=z; }
    int ao[4];
    #pragma unroll
    for (int rt=0;rt<4;++rt){
        int p = rowbase + rt*16 + l15; p = (p < P) ? p : P-1;
        ao[rt] = p*st + lg*8;
    }
    const int mb0 = (cg*32 + l15)*DH + lg*8;
    const int mb1 = mb0 + 16*DH;
    #pragma unroll 2
    for (int kst=0; kst<8; ++kst){
        const int ko = kst*32;
        f16x8 bh0 = *(const f16x8*)(B1h + mb0 + ko);
        f16x8 bl0 = *(const f16x8*)(B1l + mb0 + ko);
        f16x8 bh1 = *(const f16x8*)(B1h + mb1 + ko);
        f16x8 bl1 = *(const f16x8*)(B1l + mb1 + ko);
        #pragma unroll
        for (int rt=0;rt<4;++rt){
            f16x8 ah = *(const f16x8*)(Hh + ao[rt] + ko);
            f16x8 al = *(const f16x8*)(Hl + ao[rt] + ko);
            a0[rt] = mfma3(ah, al, bh0, bl0, a0[rt]);
            a1[rt] = mfma3(ah, al, bh1, bl1, a1[rt]);
        }
    }
    const int j = cg*16 + l15;
    const float bgc = b1[cg*32 + l15];
    const float bgo = b1[cg*32 + 16 + l15];
    #pragma unroll
    for (int rt=0;rt<4;++rt){
      #pragma unroll
      for (int reg=0;reg<4;++reg){
        const int p = rowbase + rt*16 + lg*4 + reg;
        if (p < P){
            float gc = a0[rt][reg] + bgc;
            float go = a1[rt][reg] + bgo;
            float cl = sigm(gc) * C[p*st + j];
            float hl = sigm(go) * tanhf(cl);
            C[p*st + j] = cl;                    // K2 kernel reads cl
            f16 hh = (f16)hl;
            HLh[p*DH + j] = hh;
            HLl[p*DH + j] = (f16)(hl - (float)hh);
        }
      }
    }
}

// ---- big-level K2: parent combine, A = [h_odd | hl]. grid (P/64, 4) ----
__global__ __launch_bounds__(256) void k2_kernel(
    f16* __restrict__ Hh, f16* __restrict__ Hl, float* __restrict__ C,
    const f16* __restrict__ HLh, const f16* __restrict__ HLl,
    const f16* __restrict__ B2h, const f16* __restrict__ B2l, const float* __restrict__ b2,
    const int s, const int P)
{
    const int tid = threadIdx.x, lane = tid & 63, w = tid >> 6;
    const int cg = blockIdx.y*4 + w;
    const int l15 = lane & 15, lg = lane >> 4;
    const int rowbase = blockIdx.x * 64;
    const int st = 2*s*DH;

    f32x4 g0[4], g1[4], g2[4];
    #pragma unroll
    for (int rt=0;rt<4;++rt){ f32x4 z={0.f,0.f,0.f,0.f}; g0[rt]=z; g1[rt]=z; g2[rt]=z; }
    int aoO[4], aoL[4];
    #pragma unroll
    for (int rt=0;rt<4;++rt){
        int p = rowbase + rt*16 + l15; p = (p < P) ? p : P-1;
        aoO[rt] = p*st + s*DH + lg*8;
        aoL[rt] = p*DH + lg*8;
    }
    const int ms0 = (cg*48 + l15)*512 + lg*8;
    const int ms1 = ms0 + 16*512;
    const int ms2 = ms1 + 16*512;
    #pragma unroll 2
    for (int kst=0; kst<8; ++kst){
        const int ko = kst*32;
        f16x8 bh0 = *(const f16x8*)(B2h + ms0 + ko);
        f16x8 bl0 = *(const f16x8*)(B2l + ms0 + ko);
        f16x8 bh1 = *(const f16x8*)(B2h + ms1 + ko);
        f16x8 bl1 = *(const f16x8*)(B2l + ms1 + ko);
        f16x8 bh2 = *(const f16x8*)(B2h + ms2 + ko);
        f16x8 bl2 = *(const f16x8*)(B2l + ms2 + ko);
        #pragma unroll
        for (int rt=0;rt<4;++rt){
            f16x8 ah = *(const f16x8*)(Hh + aoO[rt] + ko);
            f16x8 al = *(const f16x8*)(Hl + aoO[rt] + ko);
            g0[rt] = mfma3(ah, al, bh0, bl0, g0[rt]);
            g1[rt] = mfma3(ah, al, bh1, bl1, g1[rt]);
            g2[rt] = mfma3(ah, al, bh2, bl2, g2[rt]);
        }
    }
    #pragma unroll 2
    for (int kst=0; kst<8; ++kst){
        const int ko = kst*32;
        const int kb = (kst+8)*32;
        f16x8 bh0 = *(const f16x8*)(B2h + ms0 + kb);
        f16x8 bl0 = *(const f16x8*)(B2l + ms0 + kb);
        f16x8 bh1 = *(const f16x8*)(B2h + ms1 + kb);
        f16x8 bl1 = *(const f16x8*)(B2l + ms1 + kb);
        f16x8 bh2 = *(const f16x8*)(B2h + ms2 + kb);
        f16x8 bl2 = *(const f16x8*)(B2l + ms2 + kb);
        #pragma unroll
        for (int rt=0;rt<4;++rt){
            f16x8 ah = *(const f16x8*)(HLh + aoL[rt] + ko);
            f16x8 al = *(const f16x8*)(HLl + aoL[rt] + ko);
            g0[rt] = mfma3(ah, al, bh0, bl0, g0[rt]);
            g1[rt] = mfma3(ah, al, bh1, bl1, g1[rt]);
            g2[rt] = mfma3(ah, al, bh2, bl2, g2[rt]);
        }
    }
    const int j = cg*16 + l15;
    const float bgs = b2[cg*48 + l15];
    const float bgc = b2[cg*48 + 16 + l15];
    const float bgo = b2[cg*48 + 32 + l15];
    #pragma unroll
    for (int rt=0;rt<4;++rt){
      #pragma unroll
      for (int reg=0;reg<4;++reg){
        const int p = rowbase + rt*16 + lg*4 + reg;
        if (p < P){
            float gs = g0[rt][reg] + bgs;
            float gc = g1[rt][reg] + bgc;
            float go = g2[rt][reg] + bgo;
            float cn = sigm(gc)*C[p*st + s*DH + j] + sigm(gs)*C[p*st + j];
            float hn = sigm(go)*tanhf(cn);
            C[p*st + j] = cn;
            f16 hh = (f16)hn;
            Hh[p*st + j] = hh;
            Hl[p*st + j] = (f16)(hn - (float)hh);
        }
      }
    }
}

// ---- persistent small-tree kernel: P=256..1 + root, 16 blocks, weights in LDS ----
// Block b owns output cols [16b,16b+16). B1 rows [32b,32b+32), B2 rows [48b,48b+48)
// staged ONCE into LDS in MFMA-fragment order (1KB frags, conflict-free reads).
__global__ __launch_bounds__(512, 1) void persist_kernel(
    f16* __restrict__ Hh, f16* __restrict__ Hl, float* __restrict__ C,
    f16* __restrict__ HLh, f16* __restrict__ HLl,
    const f16* __restrict__ B1h, const f16* __restrict__ B1l,
    const f16* __restrict__ B2h, const f16* __restrict__ B2l,
    const float* __restrict__ b1, const float* __restrict__ b2,
    float* __restrict__ out, int* __restrict__ bar)
{
    __shared__ __align__(16) f16 S[65536];   // 128 KB: B1h|B1l|B2h|B2l fragments
    const int tid = threadIdx.x;
    const int b = blockIdx.x;                 // col-group 0..15
    const int w = tid >> 6, lane = tid & 63, l15 = lane & 15, lg = lane >> 4;

    // stage B1 (2 gates x 8 ksteps): frag(g,t) at S[(g*8+t)*512], lo at +8192
    for (int cid = tid; cid < 1024; cid += 512){
        int m = cid >> 5, rem = cid & 31, t = rem >> 2, o = rem & 3;
        int g = m >> 4, n = m & 15;
        int src = (b*32 + m)*DH + t*32 + o*8;
        int dst = ((g*8 + t)*64 + o*16 + n)*8;
        *(f16x8*)&S[dst]        = *(const f16x8*)(B1h + src);
        *(f16x8*)&S[8192 + dst] = *(const f16x8*)(B1l + src);
    }
    // stage B2 (3 gates x 16 ksteps): frag(g,t) at S[16384 + (g*16+t)*512], lo at +24576
    for (int cid = tid; cid < 3072; cid += 512){
        int m = cid >> 6, rem = cid & 63, t = rem >> 2, o = rem & 3;
        int g = m >> 4, n = m & 15;
        int src = (b*48 + m)*512 + t*32 + o*8;
        int dst = ((g*16 + t)*64 + o*16 + n)*8;
        *(f16x8*)&S[16384 + dst] = *(const f16x8*)(B2h + src);
        *(f16x8*)&S[40960 + dst] = *(const f16x8*)(B2l + src);
    }
    __syncthreads();

    const int j = b*16 + l15;
    const float bgc1 = b1[b*32 + l15], bgo1 = b1[b*32 + 16 + l15];
    const float bgs2 = b2[b*48 + l15], bgc2 = b2[b*48 + 16 + l15], bgo2 = b2[b*48 + 32 + l15];
    const int lane8 = lane*8;

    int s = 32;
    for (int P = 256; P >= 1; P >>= 1, s <<= 1){
        const int st = 2*s*DH;
        const int T = (P + 15) >> 4;
        float clr[2][4];
        // ---- K1 ----
        #pragma unroll
        for (int it = 0; it < 2; ++it){
            const int rt = w + it*8;
            if (rt < T){
                int p0 = rt*16 + l15; p0 = (p0 < P) ? p0 : P-1;
                const int ao = p0*st + lg*8;
                f32x4 a0 = {0.f,0.f,0.f,0.f}, a1 = {0.f,0.f,0.f,0.f};
                #pragma unroll
                for (int t = 0; t < 8; ++t){
                    f16x8 ah  = *(const f16x8*)(Hh + ao + t*32);
                    f16x8 al  = *(const f16x8*)(Hl + ao + t*32);
                    f16x8 bh0 = *(const f16x8*)&S[t*512 + lane8];
                    f16x8 bl0 = *(const f16x8*)&S[8192 + t*512 + lane8];
                    f16x8 bh1 = *(const f16x8*)&S[(8+t)*512 + lane8];
                    f16x8 bl1 = *(const f16x8*)&S[8192 + (8+t)*512 + lane8];
                    a0 = mfma3(ah, al, bh0, bl0, a0);
                    a1 = mfma3(ah, al, bh1, bl1, a1);
                }
                #pragma unroll
                for (int reg = 0; reg < 4; ++reg){
                    const int p = rt*16 + lg*4 + reg;
                    if (p < P){
                        float gc = a0[reg] + bgc1;
                        float go = a1[reg] + bgo1;
                        float cl = sigm(gc) * C[p*st + j];
                        float hl = sigm(go) * tanhf(cl);
                        clr[it][reg] = cl;
                        f16 hh = (f16)hl;
                        HLh[p*DH + j] = hh;
                        HLl[p*DH + j] = (f16)(hl - (float)hh);
                    }
                }
            }
        }
        gbar(bar, bar+1);
        // ---- K2 ----
        #pragma unroll
        for (int it = 0; it < 2; ++it){
            const int rt = w + it*8;
            if (rt < T){
                int p0 = rt*16 + l15; p0 = (p0 < P) ? p0 : P-1;
                const int aoO = p0*st + s*DH + lg*8;
                const int aoL = p0*DH + lg*8;
                f32x4 g0 = {0.f,0.f,0.f,0.f}, g1 = {0.f,0.f,0.f,0.f}, g2 = {0.f,0.f,0.f,0.f};
                #pragma unroll
                for (int t = 0; t < 8; ++t){
                    f16x8 ah  = *(const f16x8*)(Hh + aoO + t*32);
                    f16x8 al  = *(const f16x8*)(Hl + aoO + t*32);
                    f16x8 bh0 = *(const f16x8*)&S[16384 + t*512 + lane8];
                    f16x8 bl0 = *(const f16x8*)&S[40960 + t*512 + lane8];
                    f16x8 bh1 = *(const f16x8*)&S[16384 + (16+t)*512 + lane8];
                    f16x8 bl1 = *(const f16x8*)&S[40960 + (16+t)*512 + lane8];
                    f16x8 bh2 = *(const f16x8*)&S[16384 + (32+t)*512 + lane8];
                    f16x8 bl2 = *(const f16x8*)&S[40960 + (32+t)*512 + lane8];
                    g0 = mfma3(ah, al, bh0, bl0, g0);
                    g1 = mfma3(ah, al, bh1, bl1, g1);
                    g2 = mfma3(ah, al, bh2, bl2, g2);
                }
                #pragma unroll
                for (int t = 8; t < 16; ++t){
                    f16x8 ah  = *(const f16x8*)(HLh + aoL + (t-8)*32);
                    f16x8 al  = *(const f16x8*)(HLl + aoL + (t-8)*32);
                    f16x8 bh0 = *(const f16x8*)&S[16384 + t*512 + lane8];
                    f16x8 bl0 = *(const f16x8*)&S[40960 + t*512 + lane8];
                    f16x8 bh1 = *(const f16x8*)&S[16384 + (16+t)*512 + lane8];
                    f16x8 bl1 = *(const f16x8*)&S[40960 + (16+t)*512 + lane8];
                    f16x8 bh2 = *(const f16x8*)&S[16384 + (32+t)*512 + lane8];
                    f16x8 bl2 = *(const f16x8*)&S[40960 + (32+t)*512 + lane8];
                    g0 = mfma3(ah, al, bh0, bl0, g0);
                    g1 = mfma3(ah, al, bh1, bl1, g1);
                    g2 = mfma3(ah, al, bh2, bl2, g2);
                }
                #pragma unroll
                for (int reg = 0; reg < 4; ++reg){
                    const int p = rt*16 + lg*4 + reg;
                    if (p < P){
                        float gs = g0[reg] + bgs2;
                        float gc = g1[reg] + bgc2;
                        float go = g2[reg] + bgo2;
                        float cn = sigm(gc)*C[p*st + s*DH + j] + sigm(gs)*clr[it][reg];
                        float hn = sigm(go)*tanhf(cn);
                        C[p*st + j] = cn;
                        f16 hh = (f16)hn;
                        Hh[p*st + j] = hh;
                        Hl[p*st + j] = (f16)(hn - (float)hh);
                    }
                }
            }
        }
        gbar(bar, bar+1);
    }

    // ---- root: K1-type combine (sibling=0) on slot 0, block b -> out[16b..16b+16) ----
    if (w == 0){
        f32x4 a0 = {0.f,0.f,0.f,0.f}, a1 = {0.f,0.f,0.f,0.f};
        #pragma unroll
        for (int t = 0; t < 8; ++t){
            f16x8 ah  = *(const f16x8*)(Hh + lg*8 + t*32);   // all lanes row 0
            f16x8 al  = *(const f16x8*)(Hl + lg*8 + t*32);
            f16x8 bh0 = *(const f16x8*)&S[t*512 + lane8];
            f16x8 bl0 = *(const f16x8*)&S[8192 + t*512 + lane8];
            f16x8 bh1 = *(const f16x8*)&S[(8+t)*512 + lane8];
            f16x8 bl1 = *(const f16x8*)&S[8192 + (8+t)*512 + lane8];
            a0 = mfma3(ah, al, bh0, bl0, a0);
            a1 = mfma3(ah, al, bh1, bl1, a1);
        }
        if (lg == 0){
            float gc = a0[0] + bgc1;
            float go = a1[0] + bgo1;
            float cl = sigm(gc) * C[j];
            out[j] = sigm(go) * tanhf(cl);
        }
    }
}

extern "C" void kernel_launch(void* const* d_in, const int* in_sizes, int n_in,
                              void* d_out, int out_size, void* d_ws, size_t ws_size,
                              hipStream_t stream){
    const int* wid = (const int*)d_in[0];
    const float* emb = (const float*)d_in[1];
    const float* Wx = (const float*)d_in[2];
    const float* bx = (const float*)d_in[3];
    const float* Ws = (const float*)d_in[4];
    const float* bs = (const float*)d_in[5];
    const float* Wc = (const float*)d_in[6];
    const float* bc = (const float*)d_in[7];
    float* out = (float*)d_out;

    char* p = (char*)d_ws;
    auto alloc = [&](size_t bytes){ void* r = (void*)p; p += (bytes + 255) & ~255ULL; return r; };
    int*   bar = (int*)alloc(256);
    f16*   Hh  = (f16*)alloc((size_t)NLEAF*DH*2);
    f16*   Hl  = (f16*)alloc((size_t)NLEAF*DH*2);
    float* C   = (float*)alloc((size_t)NLEAF*DH*4);
    // union: X (leaf staging, 21 MB) aliased with HL (tree stage, 8.4 MB)
    char*  U   = (char*)alloc((size_t)NLEAF*KL*2*2);
    f16*   Xh  = (f16*)U;
    f16*   Xl  = (f16*)(U + (size_t)NLEAF*KL*2);
    f16*   HLh = (f16*)U;
    f16*   HLl = (f16*)(U + (size_t)(NLEAF/2)*DH*2);
    f16* BLh = (f16*)alloc((size_t)G3*KL*2); f16* BLl = (f16*)alloc((size_t)G3*KL*2);
    f16* B1h = (f16*)alloc((size_t)512*DH*2); f16* B1l = (f16*)alloc((size_t)512*DH*2);
    f16* B2h = (f16*)alloc((size_t)G3*512*2); f16* B2l = (f16*)alloc((size_t)G3*512*2);
    float* bL = (float*)alloc(G3*4);
    float* b1 = (float*)alloc(512*4);
    float* b2 = (float*)alloc(G3*4);

    const int nprep = G3*KL + 512*DH + G3*512 + G3 + 512 + G3;
    prep_kernel<<<(nprep+255)/256, 256, 0, stream>>>(Wx,Wc,Ws,bx,bs,bc,
        BLh,BLl,B1h,B1l,B2h,B2l,bL,b1,b2,bar);
    gather_kernel<<<(NLEAF*KL)/256, 256, 0, stream>>>(wid, emb, Xh, Xl);
    leaf_kernel<<<dim3(NLEAF/64, 4), 256, 0, stream>>>(Xh, Xl, BLh, BLl, bL, Hh, Hl, C);

    int s = 1;
    for (int P = NLEAF/2; P >= 512; P >>= 1){
        k1_kernel<<<dim3(P/64, 4), 256, 0, stream>>>(Hh,Hl,C, B1h,B1l,b1, HLh,HLl, s,P);
        k2_kernel<<<dim3(P/64, 4), 256, 0, stream>>>(Hh,Hl,C, HLh,HLl, B2h,B2l,b2, s,P);
        s <<= 1;
    }
    persist_kernel<<<PNB, 512, 0, stream>>>(Hh,Hl,C, HLh,HLl,
        B1h,B1l,B2h,B2l, b1,b2, out, bar);
}